// Round 5
// baseline (559.726 us; speedup 1.0000x reference)
//
#include <hip/hip_runtime.h>
#include <math.h>

// SpaMamba: row-mamba (scan along W) -> col-mamba (scan along H) -> GroupNorm+SiLU
// B=8, C=128, H=64, W=64, D_INNER=256, D_STATE=16, D_CONV=4, DT_RANK=8, GROUPS=4
//
// GEMMs run on the matrix pipe via split-bf16 (hi+lo) x3 MFMA.
// Scan: 4-way state-split, one thread per (seq, d, s-quarter); y via shfl_xor.

#define SILU(x) ((x) / (1.f + expf(-(x))))

typedef __attribute__((ext_vector_type(8))) short short8v;
typedef __attribute__((ext_vector_type(16))) float floatx16;

__device__ inline unsigned f32bits(float x) { return __builtin_bit_cast(unsigned, x); }
__device__ inline float bits32f(unsigned x) { return __builtin_bit_cast(float, x); }

// ---------------- MFMA split-bf16 GEMM:  C[n][j] = sum_k A[n,k] * W[j*K+k] ----------
template <int NT>
__global__ __launch_bounds__(256) void mfma_gemm(
    const float* __restrict__ A, const float* __restrict__ Wm, float* __restrict__ Cc,
    int NO, int NJ, int K, int SB, int S1, int S0, int SK, int KCONTIG) {
  __shared__ __align__(16) short Ah[128][40];
  __shared__ __align__(16) short Al[128][40];
  __shared__ __align__(16) short Wh[NT][40];
  __shared__ __align__(16) short Wl[NT][40];

  const int tid = threadIdx.x;
  const int lane = tid & 63, wave = tid >> 6;
  const int n0 = blockIdx.x * 128;
  const int j0 = blockIdx.y * NT;
  constexpr int NTW = NT / 2;
  constexpr int NSUB = NTW / 32;
  const int m_wave = (wave & 1) * 64;
  const int n_wave = (wave >> 1) * NTW;

  floatx16 acc[2][NSUB];
#pragma unroll
  for (int mt = 0; mt < 2; mt++)
#pragma unroll
    for (int nt = 0; nt < NSUB; nt++)
#pragma unroll
      for (int r = 0; r < 16; r++) acc[mt][nt][r] = 0.f;

  int mA, ksA;
  if (KCONTIG) { mA = tid >> 1; ksA = (tid & 1) * 16; }
  else         { mA = tid & 127; ksA = (tid >> 7) * 16; }
  const int nA = n0 + mA;
  const int bA = nA >> 12, m1A = (nA >> 6) & 63, m0A = nA & 63;
  const float* aRow = A + (size_t)bA * SB + (size_t)m1A * S1 + (size_t)m0A * S0;
  const int jW = tid >> 1, ksW = (tid & 1) * 16;

  const int half = lane >> 5;
  const int lrow = lane & 31;

  for (int kc = 0; kc < K; kc += 32) {
    float v[16];
    if (KCONTIG) {
      const float4* p4 = (const float4*)(aRow + kc + ksA);
#pragma unroll
      for (int q = 0; q < 4; q++) {
        float4 t = p4[q];
        v[q * 4 + 0] = t.x; v[q * 4 + 1] = t.y; v[q * 4 + 2] = t.z; v[q * 4 + 3] = t.w;
      }
    } else {
      const float* p = aRow + (size_t)(kc + ksA) * SK;
#pragma unroll
      for (int i = 0; i < 16; i++) v[i] = p[(size_t)i * SK];
    }
    unsigned uh[8], ul[8];
#pragma unroll
    for (int i = 0; i < 8; i++) {
      unsigned a0 = f32bits(v[2 * i]), a1 = f32bits(v[2 * i + 1]);
      uh[i] = __builtin_amdgcn_perm(a1, a0, 0x07060302);
      float l0 = v[2 * i] - bits32f(a0 & 0xFFFF0000u);
      float l1 = v[2 * i + 1] - bits32f(a1 & 0xFFFF0000u);
      ul[i] = __builtin_amdgcn_perm(f32bits(l1), f32bits(l0), 0x07060302);
    }
    {
      char* dh = (char*)Ah + (size_t)mA * 80 + ksA * 2;
      char* dl = (char*)Al + (size_t)mA * 80 + ksA * 2;
      ((uint4*)dh)[0] = make_uint4(uh[0], uh[1], uh[2], uh[3]);
      ((uint4*)dh)[1] = make_uint4(uh[4], uh[5], uh[6], uh[7]);
      ((uint4*)dl)[0] = make_uint4(ul[0], ul[1], ul[2], ul[3]);
      ((uint4*)dl)[1] = make_uint4(ul[4], ul[5], ul[6], ul[7]);
    }
    if (jW < NT) {
      float wv[16];
      if (j0 + jW < NJ) {
        const float4* p4 = (const float4*)(Wm + (size_t)(j0 + jW) * K + kc + ksW);
#pragma unroll
        for (int q = 0; q < 4; q++) {
          float4 t = p4[q];
          wv[q * 4 + 0] = t.x; wv[q * 4 + 1] = t.y; wv[q * 4 + 2] = t.z; wv[q * 4 + 3] = t.w;
        }
      } else {
#pragma unroll
        for (int i = 0; i < 16; i++) wv[i] = 0.f;
      }
      unsigned wh[8], wl[8];
#pragma unroll
      for (int i = 0; i < 8; i++) {
        unsigned a0 = f32bits(wv[2 * i]), a1 = f32bits(wv[2 * i + 1]);
        wh[i] = __builtin_amdgcn_perm(a1, a0, 0x07060302);
        float l0 = wv[2 * i] - bits32f(a0 & 0xFFFF0000u);
        float l1 = wv[2 * i + 1] - bits32f(a1 & 0xFFFF0000u);
        wl[i] = __builtin_amdgcn_perm(f32bits(l1), f32bits(l0), 0x07060302);
      }
      char* dh = (char*)Wh + (size_t)jW * 80 + ksW * 2;
      char* dl = (char*)Wl + (size_t)jW * 80 + ksW * 2;
      ((uint4*)dh)[0] = make_uint4(wh[0], wh[1], wh[2], wh[3]);
      ((uint4*)dh)[1] = make_uint4(wh[4], wh[5], wh[6], wh[7]);
      ((uint4*)dl)[0] = make_uint4(wl[0], wl[1], wl[2], wl[3]);
      ((uint4*)dl)[1] = make_uint4(wl[4], wl[5], wl[6], wl[7]);
    }
    __syncthreads();

#pragma unroll
    for (int s = 0; s < 2; s++) {
      const int koff = s * 32 + half * 16;
      short8v afh[2], afl[2], wfh[NSUB], wfl[NSUB];
#pragma unroll
      for (int mt = 0; mt < 2; mt++) {
        int mr = m_wave + mt * 32 + lrow;
        afh[mt] = *(const short8v*)((const char*)Ah + (size_t)mr * 80 + koff);
        afl[mt] = *(const short8v*)((const char*)Al + (size_t)mr * 80 + koff);
      }
#pragma unroll
      for (int nt = 0; nt < NSUB; nt++) {
        int nr = n_wave + nt * 32 + lrow;
        wfh[nt] = *(const short8v*)((const char*)Wh + (size_t)nr * 80 + koff);
        wfl[nt] = *(const short8v*)((const char*)Wl + (size_t)nr * 80 + koff);
      }
#pragma unroll
      for (int mt = 0; mt < 2; mt++)
#pragma unroll
        for (int nt = 0; nt < NSUB; nt++) {
          acc[mt][nt] = __builtin_amdgcn_mfma_f32_32x32x16_bf16(afh[mt], wfh[nt], acc[mt][nt], 0, 0, 0);
          acc[mt][nt] = __builtin_amdgcn_mfma_f32_32x32x16_bf16(afh[mt], wfl[nt], acc[mt][nt], 0, 0, 0);
          acc[mt][nt] = __builtin_amdgcn_mfma_f32_32x32x16_bf16(afl[mt], wfh[nt], acc[mt][nt], 0, 0, 0);
        }
    }
    __syncthreads();
  }

#pragma unroll
  for (int mt = 0; mt < 2; mt++)
#pragma unroll
    for (int nt = 0; nt < NSUB; nt++) {
      int col = j0 + n_wave + nt * 32 + lrow;
      if (col < NJ) {
#pragma unroll
        for (int r = 0; r < 16; r++) {
          int row = n0 + m_wave + mt * 32 + (r & 3) + 8 * (r >> 2) + 4 * half;
          Cc[(size_t)row * NO + col] = acc[mt][nt][r];
        }
      }
    }
}

// ---------------- causal depthwise conv (k=4) + bias + silu -----------------
__global__ __launch_bounds__(256) void conv_silu_kernel(
    const float* __restrict__ xz, const float* __restrict__ cw,
    const float* __restrict__ cb, float* __restrict__ xc) {
  int n = blockIdx.x;
  int d = threadIdx.x;
  int w = n & 63;
  float acc = cb[d];
  const float* cwd = cw + d * 4;
#pragma unroll
  for (int k = 0; k < 4; k++) {
    int ws = w - 3 + k;
    if (ws >= 0) acc = fmaf(xz[(n - 3 + k) * 512 + d], cwd[k], acc);
  }
  xc[n * 256 + d] = SILU(acc);
}

// ---------------- dt expansion: dt = softplus(xdbl[:, :8] @ Wdt.T + bdt) -----------
__global__ __launch_bounds__(256) void dt_expand_kernel(
    const float* __restrict__ xdbl, const float* __restrict__ Wdt,
    const float* __restrict__ bdt, float* __restrict__ dt) {
  __shared__ float lx[64][8];
  int n0 = blockIdx.x * 64, t = threadIdx.x;
#pragma unroll
  for (int i = 0; i < 2; i++) {
    int idx = t + i * 256;
    int n = idx >> 3, r = idx & 7;
    lx[n][r] = xdbl[(n0 + n) * 40 + r];
  }
  float w[8];
#pragma unroll
  for (int r = 0; r < 8; r++) w[r] = Wdt[t * 8 + r];
  float bb = bdt[t];
  __syncthreads();
  for (int n = 0; n < 64; n++) {
    float acc = bb;
#pragma unroll
    for (int r = 0; r < 8; r++) acc = fmaf(lx[n][r], w[r], acc);
    dt[(n0 + n) * 256 + t] = fmaxf(acc, 0.f) + log1pf(expf(-fabsf(acc)));
  }
}

// ---------------- SSM scan, 4-way state split ----------------
// thread = (seq, d, sq); 4 states each; y reduced over sq via shfl_xor(1),(2).
// grid 2048 blocks: block = (seq, 64-channel slice). 8 waves/SIMD occupancy.
__global__ __launch_bounds__(256) void scan_kernel(
    const float* __restrict__ dtb, const float* __restrict__ xcb,
    const float* __restrict__ xzb, const float* __restrict__ xdbl,
    const float* __restrict__ Alog, const float* __restrict__ Dv,
    float* __restrict__ ydt) {
  __shared__ float lbc[64 * 32];
  int seq = blockIdx.x >> 2;
  int dblk = (blockIdx.x & 3) * 64;
  int t = threadIdx.x;
  int base = seq * 64;
#pragma unroll
  for (int i = 0; i < 8; i++) {
    int idx = t + i * 256;
    int w = idx >> 5, s = idx & 31;
    lbc[idx] = xdbl[(base + w) * 40 + 8 + s];
  }
  const int dl = t >> 2;        // 0..63
  const int sq = t & 3;         // state quarter
  const int d = dblk + dl;
  float As[4];
#pragma unroll
  for (int j = 0; j < 4; j++) As[j] = -expf(Alog[d * 16 + sq * 4 + j]);
  const float Dd = Dv[d];
  float h0 = 0.f, h1 = 0.f, h2 = 0.f, h3 = 0.f;
  __syncthreads();

  const int idx0 = base * 256 + d;
  float dtv = dtb[idx0];
  float xcv = xcb[idx0];
  float zv  = xzb[base * 512 + 256 + d];
#pragma unroll 4
  for (int w = 0; w < 64; w++) {
    float dtn = 0.f, xcn = 0.f, zn = 0.f;
    if (w < 63) {                         // prefetch next step off the chain
      int idxn = idx0 + (w + 1) * 256;
      dtn = dtb[idxn];
      xcn = xcb[idxn];
      zn  = xzb[(base + w + 1) * 512 + 256 + d];
    }
    float dx = dtv * xcv;
    const float4 B4 = *(const float4*)(lbc + w * 32 + sq * 4);
    const float4 C4 = *(const float4*)(lbc + w * 32 + 16 + sq * 4);
    float e0 = expf(dtv * As[0]);
    float e1 = expf(dtv * As[1]);
    float e2 = expf(dtv * As[2]);
    float e3 = expf(dtv * As[3]);
    h0 = fmaf(h0, e0, dx * B4.x);
    h1 = fmaf(h1, e1, dx * B4.y);
    h2 = fmaf(h2, e2, dx * B4.z);
    h3 = fmaf(h3, e3, dx * B4.w);
    float yv = h0 * C4.x + h1 * C4.y + h2 * C4.z + h3 * C4.w;
    yv += __shfl_xor(yv, 1);
    yv += __shfl_xor(yv, 2);
    if (sq == 0) ydt[idx0 + w * 256] = (yv + xcv * Dd) * SILU(zv);
    dtv = dtn; xcv = xcn; zv = zn;
  }
}

// ---------------- GroupNorm stats, two-stage ----------------
__global__ __launch_bounds__(256) void gn_partial_kernel(
    const float* __restrict__ s2, double* __restrict__ partials) {
  int bg = blockIdx.x >> 6, sub = blockIdx.x & 63;
  int b = bg >> 2, g = bg & 3;
  int t = threadIdx.x;
  const float* basep = s2 + b * 524288 + g * 32 + sub * 64 * 128;
  double sum = 0.0, sumsq = 0.0;
#pragma unroll
  for (int i = 0; i < 8; i++) {
    int idx = t + i * 256;
    int c = idx & 31, sp = idx >> 5;
    float v = basep[sp * 128 + c];
    sum += v;
    sumsq += (double)v * v;
  }
  __shared__ double ls[256], lq[256];
  ls[t] = sum; lq[t] = sumsq;
  __syncthreads();
  for (int o = 128; o > 0; o >>= 1) {
    if (t < o) { ls[t] += ls[t + o]; lq[t] += lq[t + o]; }
    __syncthreads();
  }
  if (t == 0) {
    partials[blockIdx.x * 2]     = ls[0];
    partials[blockIdx.x * 2 + 1] = lq[0];
  }
}

__global__ __launch_bounds__(64) void gn_final_kernel(
    const double* __restrict__ partials, float* __restrict__ stats) {
  int bg = blockIdx.x, t = threadIdx.x;
  __shared__ double ls[64], lq[64];
  ls[t] = partials[(bg * 64 + t) * 2];
  lq[t] = partials[(bg * 64 + t) * 2 + 1];
  __syncthreads();
  for (int o = 32; o > 0; o >>= 1) {
    if (t < o) { ls[t] += ls[t + o]; lq[t] += lq[t + o]; }
    __syncthreads();
  }
  if (t == 0) {
    double mu = ls[0] / 131072.0;
    double var = lq[0] / 131072.0 - mu * mu;
    stats[bg * 2] = (float)mu;
    stats[bg * 2 + 1] = (float)(1.0 / sqrt(var + 1e-5));
  }
}

// ---------------- GN apply + silu, with LDS transpose (b,w,h,c) -> (b,c,h,w) --------
__global__ __launch_bounds__(256) void gn_apply_kernel(
    const float* __restrict__ s2, const float* __restrict__ stats,
    const float* __restrict__ gamma, const float* __restrict__ beta,
    float* __restrict__ out) {
  __shared__ float tile[64 * 129];
  int b = blockIdx.x >> 6, hh = blockIdx.x & 63;
  int t = threadIdx.x;
  const float* src = s2 + b * 524288 + hh * 128;
#pragma unroll
  for (int i = 0; i < 32; i++) {
    int idx = t + i * 256;
    int c = idx & 127, w = idx >> 7;
    tile[w * 129 + c] = src[w * 8192 + c];
  }
  __syncthreads();
  float* dst = out + b * 524288 + hh * 64;
#pragma unroll
  for (int i = 0; i < 32; i++) {
    int idx = t + i * 256;
    int w = idx & 63, c = idx >> 6;
    int g = c >> 5;
    float mu = stats[(b * 4 + g) * 2];
    float rs = stats[(b * 4 + g) * 2 + 1];
    float v = fmaf((tile[w * 129 + c] - mu) * rs, gamma[c], beta[c]);
    dst[c * 4096 + w] = SILU(v);
  }
}

extern "C" void kernel_launch(void* const* d_in, const int* in_sizes, int n_in,
                              void* d_out, int out_size, void* d_ws, size_t ws_size,
                              hipStream_t stream) {
  const float* x = (const float*)d_in[0];
  const float* rWin  = (const float*)d_in[1];
  const float* rcw   = (const float*)d_in[2];
  const float* rcb   = (const float*)d_in[3];
  const float* rWx   = (const float*)d_in[4];
  const float* rWdt  = (const float*)d_in[5];
  const float* rbdt  = (const float*)d_in[6];
  const float* rAlog = (const float*)d_in[7];
  const float* rD    = (const float*)d_in[8];
  const float* rWout = (const float*)d_in[9];
  const float* cWin  = (const float*)d_in[10];
  const float* ccw   = (const float*)d_in[11];
  const float* ccb   = (const float*)d_in[12];
  const float* cWx   = (const float*)d_in[13];
  const float* cWdt  = (const float*)d_in[14];
  const float* cbdt  = (const float*)d_in[15];
  const float* cAlog = (const float*)d_in[16];
  const float* cD    = (const float*)d_in[17];
  const float* cWout = (const float*)d_in[18];
  const float* gamma = (const float*)d_in[19];
  const float* beta  = (const float*)d_in[20];
  float* out = (float*)d_out;

  float* ws = (float*)d_ws;
  float* xz    = ws;                    // 16,777,216
  float* xc    = xz  + 16777216;        //  8,388,608
  float* dt    = xc  + 8388608;         //  8,388,608
  float* st1   = dt  + 8388608;         //  4,194,304
  float* stats = st1 + 4194304;         //  64
  double* partials = (double*)(stats + 64);
  float* xdbl  = st1;                   // overlay: st1 dead while xdbl lives
  float* st2   = xc;                    // overlay: xc dead when stage2 written

  auto run_mamba = [&](const float* A, int SB, int S1, int S0, int SK, int KCONTIG,
                       const float* Win, const float* cw, const float* cb,
                       const float* Wx, const float* Wdt, const float* bdt,
                       const float* Alog, const float* Dv, const float* Wout,
                       float* outp) {
    mfma_gemm<128><<<dim3(256, 4), 256, 0, stream>>>(A, Win, xz, 512, 512, 128,
                                                     SB, S1, S0, SK, KCONTIG);
    conv_silu_kernel<<<32768, 256, 0, stream>>>(xz, cw, cb, xc);
    mfma_gemm<64><<<dim3(256, 1), 256, 0, stream>>>(xc, Wx, xdbl, 40, 40, 256,
                                                    1048576, 16384, 256, 1, 1);
    dt_expand_kernel<<<512, 256, 0, stream>>>(xdbl, Wdt, bdt, dt);
    scan_kernel<<<2048, 256, 0, stream>>>(dt, xc, xz, xdbl, Alog, Dv, dt);
    mfma_gemm<128><<<dim3(256, 1), 256, 0, stream>>>(dt, Wout, outp, 128, 128, 256,
                                                     1048576, 16384, 256, 1, 1);
  };

  // row phase: A[n,k] = x[b,k,h,w], n=(b,h,w)
  run_mamba(x, 524288, 64, 1, 4096, 0,
            rWin, rcw, rcb, rWx, rWdt, rbdt, rAlog, rD, rWout, st1);
  // col phase: A[n,k] = st1[b,h,w,k], n=(b,w,h)
  run_mamba(st1, 524288, 128, 8192, 1, 1,
            cWin, ccw, ccb, cWx, cWdt, cbdt, cAlog, cD, cWout, st2);

  gn_partial_kernel<<<2048, 256, 0, stream>>>(st2, partials);
  gn_final_kernel<<<32, 64, 0, stream>>>(partials, stats);
  gn_apply_kernel<<<512, 256, 0, stream>>>(st2, stats, gamma, beta, out);
}

// Round 6
// 487.493 us; speedup vs baseline: 1.1482x; 1.1482x over previous
//
#include <hip/hip_runtime.h>
#include <math.h>

// SpaMamba: row-mamba (scan along W) -> col-mamba (scan along H) -> GroupNorm+SiLU
// B=8, C=128, H=64, W=64, D_INNER=256, D_STATE=16, D_CONV=4, DT_RANK=8, GROUPS=4
//
// GEMMs run on the matrix pipe via split-bf16 (hi+lo) x3 MFMA.
// Scan: 4-way state-split + depth-4 register prefetch pipeline + __expf.

#define SILU(x) ((x) / (1.f + expf(-(x))))

typedef __attribute__((ext_vector_type(8))) short short8v;
typedef __attribute__((ext_vector_type(16))) float floatx16;

__device__ inline unsigned f32bits(float x) { return __builtin_bit_cast(unsigned, x); }
__device__ inline float bits32f(unsigned x) { return __builtin_bit_cast(float, x); }

// ---------------- MFMA split-bf16 GEMM:  C[n][j] = sum_k A[n,k] * W[j*K+k] ----------
template <int NT>
__global__ __launch_bounds__(256) void mfma_gemm(
    const float* __restrict__ A, const float* __restrict__ Wm, float* __restrict__ Cc,
    int NO, int NJ, int K, int SB, int S1, int S0, int SK, int KCONTIG) {
  __shared__ __align__(16) short Ah[128][40];
  __shared__ __align__(16) short Al[128][40];
  __shared__ __align__(16) short Wh[NT][40];
  __shared__ __align__(16) short Wl[NT][40];

  const int tid = threadIdx.x;
  const int lane = tid & 63, wave = tid >> 6;
  const int n0 = blockIdx.x * 128;
  const int j0 = blockIdx.y * NT;
  constexpr int NTW = NT / 2;
  constexpr int NSUB = NTW / 32;
  const int m_wave = (wave & 1) * 64;
  const int n_wave = (wave >> 1) * NTW;

  floatx16 acc[2][NSUB];
#pragma unroll
  for (int mt = 0; mt < 2; mt++)
#pragma unroll
    for (int nt = 0; nt < NSUB; nt++)
#pragma unroll
      for (int r = 0; r < 16; r++) acc[mt][nt][r] = 0.f;

  int mA, ksA;
  if (KCONTIG) { mA = tid >> 1; ksA = (tid & 1) * 16; }
  else         { mA = tid & 127; ksA = (tid >> 7) * 16; }
  const int nA = n0 + mA;
  const int bA = nA >> 12, m1A = (nA >> 6) & 63, m0A = nA & 63;
  const float* aRow = A + (size_t)bA * SB + (size_t)m1A * S1 + (size_t)m0A * S0;
  const int jW = tid >> 1, ksW = (tid & 1) * 16;

  const int half = lane >> 5;
  const int lrow = lane & 31;

  for (int kc = 0; kc < K; kc += 32) {
    float v[16];
    if (KCONTIG) {
      const float4* p4 = (const float4*)(aRow + kc + ksA);
#pragma unroll
      for (int q = 0; q < 4; q++) {
        float4 t = p4[q];
        v[q * 4 + 0] = t.x; v[q * 4 + 1] = t.y; v[q * 4 + 2] = t.z; v[q * 4 + 3] = t.w;
      }
    } else {
      const float* p = aRow + (size_t)(kc + ksA) * SK;
#pragma unroll
      for (int i = 0; i < 16; i++) v[i] = p[(size_t)i * SK];
    }
    unsigned uh[8], ul[8];
#pragma unroll
    for (int i = 0; i < 8; i++) {
      unsigned a0 = f32bits(v[2 * i]), a1 = f32bits(v[2 * i + 1]);
      uh[i] = __builtin_amdgcn_perm(a1, a0, 0x07060302);
      float l0 = v[2 * i] - bits32f(a0 & 0xFFFF0000u);
      float l1 = v[2 * i + 1] - bits32f(a1 & 0xFFFF0000u);
      ul[i] = __builtin_amdgcn_perm(f32bits(l1), f32bits(l0), 0x07060302);
    }
    {
      char* dh = (char*)Ah + (size_t)mA * 80 + ksA * 2;
      char* dl = (char*)Al + (size_t)mA * 80 + ksA * 2;
      ((uint4*)dh)[0] = make_uint4(uh[0], uh[1], uh[2], uh[3]);
      ((uint4*)dh)[1] = make_uint4(uh[4], uh[5], uh[6], uh[7]);
      ((uint4*)dl)[0] = make_uint4(ul[0], ul[1], ul[2], ul[3]);
      ((uint4*)dl)[1] = make_uint4(ul[4], ul[5], ul[6], ul[7]);
    }
    if (jW < NT) {
      float wv[16];
      if (j0 + jW < NJ) {
        const float4* p4 = (const float4*)(Wm + (size_t)(j0 + jW) * K + kc + ksW);
#pragma unroll
        for (int q = 0; q < 4; q++) {
          float4 t = p4[q];
          wv[q * 4 + 0] = t.x; wv[q * 4 + 1] = t.y; wv[q * 4 + 2] = t.z; wv[q * 4 + 3] = t.w;
        }
      } else {
#pragma unroll
        for (int i = 0; i < 16; i++) wv[i] = 0.f;
      }
      unsigned wh[8], wl[8];
#pragma unroll
      for (int i = 0; i < 8; i++) {
        unsigned a0 = f32bits(wv[2 * i]), a1 = f32bits(wv[2 * i + 1]);
        wh[i] = __builtin_amdgcn_perm(a1, a0, 0x07060302);
        float l0 = wv[2 * i] - bits32f(a0 & 0xFFFF0000u);
        float l1 = wv[2 * i + 1] - bits32f(a1 & 0xFFFF0000u);
        wl[i] = __builtin_amdgcn_perm(f32bits(l1), f32bits(l0), 0x07060302);
      }
      char* dh = (char*)Wh + (size_t)jW * 80 + ksW * 2;
      char* dl = (char*)Wl + (size_t)jW * 80 + ksW * 2;
      ((uint4*)dh)[0] = make_uint4(wh[0], wh[1], wh[2], wh[3]);
      ((uint4*)dh)[1] = make_uint4(wh[4], wh[5], wh[6], wh[7]);
      ((uint4*)dl)[0] = make_uint4(wl[0], wl[1], wl[2], wl[3]);
      ((uint4*)dl)[1] = make_uint4(wl[4], wl[5], wl[6], wl[7]);
    }
    __syncthreads();

#pragma unroll
    for (int s = 0; s < 2; s++) {
      const int koff = s * 32 + half * 16;
      short8v afh[2], afl[2], wfh[NSUB], wfl[NSUB];
#pragma unroll
      for (int mt = 0; mt < 2; mt++) {
        int mr = m_wave + mt * 32 + lrow;
        afh[mt] = *(const short8v*)((const char*)Ah + (size_t)mr * 80 + koff);
        afl[mt] = *(const short8v*)((const char*)Al + (size_t)mr * 80 + koff);
      }
#pragma unroll
      for (int nt = 0; nt < NSUB; nt++) {
        int nr = n_wave + nt * 32 + lrow;
        wfh[nt] = *(const short8v*)((const char*)Wh + (size_t)nr * 80 + koff);
        wfl[nt] = *(const short8v*)((const char*)Wl + (size_t)nr * 80 + koff);
      }
#pragma unroll
      for (int mt = 0; mt < 2; mt++)
#pragma unroll
        for (int nt = 0; nt < NSUB; nt++) {
          acc[mt][nt] = __builtin_amdgcn_mfma_f32_32x32x16_bf16(afh[mt], wfh[nt], acc[mt][nt], 0, 0, 0);
          acc[mt][nt] = __builtin_amdgcn_mfma_f32_32x32x16_bf16(afh[mt], wfl[nt], acc[mt][nt], 0, 0, 0);
          acc[mt][nt] = __builtin_amdgcn_mfma_f32_32x32x16_bf16(afl[mt], wfh[nt], acc[mt][nt], 0, 0, 0);
        }
    }
    __syncthreads();
  }

#pragma unroll
  for (int mt = 0; mt < 2; mt++)
#pragma unroll
    for (int nt = 0; nt < NSUB; nt++) {
      int col = j0 + n_wave + nt * 32 + lrow;
      if (col < NJ) {
#pragma unroll
        for (int r = 0; r < 16; r++) {
          int row = n0 + m_wave + mt * 32 + (r & 3) + 8 * (r >> 2) + 4 * half;
          Cc[(size_t)row * NO + col] = acc[mt][nt][r];
        }
      }
    }
}

// ---------------- causal depthwise conv (k=4) + bias + silu -----------------
__global__ __launch_bounds__(256) void conv_silu_kernel(
    const float* __restrict__ xz, const float* __restrict__ cw,
    const float* __restrict__ cb, float* __restrict__ xc) {
  int n = blockIdx.x;
  int d = threadIdx.x;
  int w = n & 63;
  float acc = cb[d];
  const float* cwd = cw + d * 4;
#pragma unroll
  for (int k = 0; k < 4; k++) {
    int ws = w - 3 + k;
    if (ws >= 0) acc = fmaf(xz[(n - 3 + k) * 512 + d], cwd[k], acc);
  }
  xc[n * 256 + d] = SILU(acc);
}

// ---------------- dt expansion: dt = softplus(xdbl[:, :8] @ Wdt.T + bdt) -----------
__global__ __launch_bounds__(256) void dt_expand_kernel(
    const float* __restrict__ xdbl, const float* __restrict__ Wdt,
    const float* __restrict__ bdt, float* __restrict__ dt) {
  __shared__ float lx[64][8];
  int n0 = blockIdx.x * 64, t = threadIdx.x;
#pragma unroll
  for (int i = 0; i < 2; i++) {
    int idx = t + i * 256;
    int n = idx >> 3, r = idx & 7;
    lx[n][r] = xdbl[(n0 + n) * 40 + r];
  }
  float w[8];
#pragma unroll
  for (int r = 0; r < 8; r++) w[r] = Wdt[t * 8 + r];
  float bb = bdt[t];
  __syncthreads();
  for (int n = 0; n < 64; n++) {
    float acc = bb;
#pragma unroll
    for (int r = 0; r < 8; r++) acc = fmaf(lx[n][r], w[r], acc);
    dt[(n0 + n) * 256 + t] = fmaxf(acc, 0.f) + log1pf(expf(-fabsf(acc)));
  }
}

// ---------------- SSM scan, 4-way state split + depth-4 prefetch ----------------
// thread = (seq, d, sq); 4 states each; y reduced over sq via shfl_xor(1),(2).
// grid 2048 blocks: block = (seq, 64-channel slice).
__global__ __launch_bounds__(256) void scan_kernel(
    const float* __restrict__ dtb, const float* __restrict__ xcb,
    const float* __restrict__ xzb, const float* __restrict__ xdbl,
    const float* __restrict__ Alog, const float* __restrict__ Dv,
    float* __restrict__ ydt) {
  __shared__ float lbc[64 * 32];
  int seq = blockIdx.x >> 2;
  int dblk = (blockIdx.x & 3) * 64;
  int t = threadIdx.x;
  int base = seq * 64;
#pragma unroll
  for (int i = 0; i < 8; i++) {
    int idx = t + i * 256;
    int w = idx >> 5, s = idx & 31;
    lbc[idx] = xdbl[(base + w) * 40 + 8 + s];
  }
  const int dl = t >> 2;        // 0..63
  const int sq = t & 3;         // state quarter
  const int d = dblk + dl;
  float As[4];
#pragma unroll
  for (int j = 0; j < 4; j++) As[j] = -expf(Alog[d * 16 + sq * 4 + j]);
  const float Dd = Dv[d];
  float h0 = 0.f, h1 = 0.f, h2 = 0.f, h3 = 0.f;

  const int idx0 = base * 256 + d;
  const float* pdt = dtb + idx0;
  const float* pxc = xcb + idx0;
  const float* pz  = xzb + base * 512 + 256 + d;
  // depth-4 prefetch pipeline
  float dtp[4], xcp[4], zp[4];
#pragma unroll
  for (int i = 0; i < 4; i++) {
    dtp[i] = pdt[i * 256];
    xcp[i] = pxc[i * 256];
    zp[i]  = pz[i * 512];
  }
  __syncthreads();

#pragma unroll 4
  for (int w = 0; w < 64; w++) {
    float dtv = dtp[0], xcv = xcp[0], zv = zp[0];
    dtp[0] = dtp[1]; dtp[1] = dtp[2]; dtp[2] = dtp[3];
    xcp[0] = xcp[1]; xcp[1] = xcp[2]; xcp[2] = xcp[3];
    zp[0]  = zp[1];  zp[1]  = zp[2];  zp[2]  = zp[3];
    {
      int wn = (w + 4 < 64) ? (w + 4) : 63;   // clamped prefetch (value unused past end)
      dtp[3] = pdt[wn * 256];
      xcp[3] = pxc[wn * 256];
      zp[3]  = pz[wn * 512];
    }
    float dx = dtv * xcv;
    const float4 B4 = *(const float4*)(lbc + w * 32 + sq * 4);
    const float4 C4 = *(const float4*)(lbc + w * 32 + 16 + sq * 4);
    float e0 = __expf(dtv * As[0]);
    float e1 = __expf(dtv * As[1]);
    float e2 = __expf(dtv * As[2]);
    float e3 = __expf(dtv * As[3]);
    h0 = fmaf(h0, e0, dx * B4.x);
    h1 = fmaf(h1, e1, dx * B4.y);
    h2 = fmaf(h2, e2, dx * B4.z);
    h3 = fmaf(h3, e3, dx * B4.w);
    float yv = h0 * C4.x + h1 * C4.y + h2 * C4.z + h3 * C4.w;
    yv += __shfl_xor(yv, 1);
    yv += __shfl_xor(yv, 2);
    if (sq == 0) {
      float sz = zv / (1.f + __expf(-zv));
      ydt[idx0 + w * 256] = (yv + xcv * Dd) * sz;
    }
  }
}

// ---------------- GroupNorm stats, two-stage ----------------
__global__ __launch_bounds__(256) void gn_partial_kernel(
    const float* __restrict__ s2, double* __restrict__ partials) {
  int bg = blockIdx.x >> 6, sub = blockIdx.x & 63;
  int b = bg >> 2, g = bg & 3;
  int t = threadIdx.x;
  const float* basep = s2 + b * 524288 + g * 32 + sub * 64 * 128;
  double sum = 0.0, sumsq = 0.0;
#pragma unroll
  for (int i = 0; i < 8; i++) {
    int idx = t + i * 256;
    int c = idx & 31, sp = idx >> 5;
    float v = basep[sp * 128 + c];
    sum += v;
    sumsq += (double)v * v;
  }
  __shared__ double ls[256], lq[256];
  ls[t] = sum; lq[t] = sumsq;
  __syncthreads();
  for (int o = 128; o > 0; o >>= 1) {
    if (t < o) { ls[t] += ls[t + o]; lq[t] += lq[t + o]; }
    __syncthreads();
  }
  if (t == 0) {
    partials[blockIdx.x * 2]     = ls[0];
    partials[blockIdx.x * 2 + 1] = lq[0];
  }
}

__global__ __launch_bounds__(64) void gn_final_kernel(
    const double* __restrict__ partials, float* __restrict__ stats) {
  int bg = blockIdx.x, t = threadIdx.x;
  __shared__ double ls[64], lq[64];
  ls[t] = partials[(bg * 64 + t) * 2];
  lq[t] = partials[(bg * 64 + t) * 2 + 1];
  __syncthreads();
  for (int o = 32; o > 0; o >>= 1) {
    if (t < o) { ls[t] += ls[t + o]; lq[t] += lq[t + o]; }
    __syncthreads();
  }
  if (t == 0) {
    double mu = ls[0] / 131072.0;
    double var = lq[0] / 131072.0 - mu * mu;
    stats[bg * 2] = (float)mu;
    stats[bg * 2 + 1] = (float)(1.0 / sqrt(var + 1e-5));
  }
}

// ---------------- GN apply + silu, with LDS transpose (b,w,h,c) -> (b,c,h,w) --------
__global__ __launch_bounds__(256) void gn_apply_kernel(
    const float* __restrict__ s2, const float* __restrict__ stats,
    const float* __restrict__ gamma, const float* __restrict__ beta,
    float* __restrict__ out) {
  __shared__ float tile[64 * 129];
  int b = blockIdx.x >> 6, hh = blockIdx.x & 63;
  int t = threadIdx.x;
  const float* src = s2 + b * 524288 + hh * 128;
#pragma unroll
  for (int i = 0; i < 32; i++) {
    int idx = t + i * 256;
    int c = idx & 127, w = idx >> 7;
    tile[w * 129 + c] = src[w * 8192 + c];
  }
  __syncthreads();
  float* dst = out + b * 524288 + hh * 64;
#pragma unroll
  for (int i = 0; i < 32; i++) {
    int idx = t + i * 256;
    int w = idx & 63, c = idx >> 6;
    int g = c >> 5;
    float mu = stats[(b * 4 + g) * 2];
    float rs = stats[(b * 4 + g) * 2 + 1];
    float v = fmaf((tile[w * 129 + c] - mu) * rs, gamma[c], beta[c]);
    dst[c * 4096 + w] = SILU(v);
  }
}

extern "C" void kernel_launch(void* const* d_in, const int* in_sizes, int n_in,
                              void* d_out, int out_size, void* d_ws, size_t ws_size,
                              hipStream_t stream) {
  const float* x = (const float*)d_in[0];
  const float* rWin  = (const float*)d_in[1];
  const float* rcw   = (const float*)d_in[2];
  const float* rcb   = (const float*)d_in[3];
  const float* rWx   = (const float*)d_in[4];
  const float* rWdt  = (const float*)d_in[5];
  const float* rbdt  = (const float*)d_in[6];
  const float* rAlog = (const float*)d_in[7];
  const float* rD    = (const float*)d_in[8];
  const float* rWout = (const float*)d_in[9];
  const float* cWin  = (const float*)d_in[10];
  const float* ccw   = (const float*)d_in[11];
  const float* ccb   = (const float*)d_in[12];
  const float* cWx   = (const float*)d_in[13];
  const float* cWdt  = (const float*)d_in[14];
  const float* cbdt  = (const float*)d_in[15];
  const float* cAlog = (const float*)d_in[16];
  const float* cD    = (const float*)d_in[17];
  const float* cWout = (const float*)d_in[18];
  const float* gamma = (const float*)d_in[19];
  const float* beta  = (const float*)d_in[20];
  float* out = (float*)d_out;

  float* ws = (float*)d_ws;
  float* xz    = ws;                    // 16,777,216
  float* xc    = xz  + 16777216;        //  8,388,608
  float* dt    = xc  + 8388608;         //  8,388,608
  float* st1   = dt  + 8388608;         //  4,194,304
  float* stats = st1 + 4194304;         //  64
  double* partials = (double*)(stats + 64);
  float* xdbl  = st1;                   // overlay: st1 dead while xdbl lives
  float* st2   = xc;                    // overlay: xc dead when stage2 written

  auto run_mamba = [&](const float* A, int SB, int S1, int S0, int SK, int KCONTIG,
                       const float* Win, const float* cw, const float* cb,
                       const float* Wx, const float* Wdt, const float* bdt,
                       const float* Alog, const float* Dv, const float* Wout,
                       float* outp) {
    mfma_gemm<128><<<dim3(256, 4), 256, 0, stream>>>(A, Win, xz, 512, 512, 128,
                                                     SB, S1, S0, SK, KCONTIG);
    conv_silu_kernel<<<32768, 256, 0, stream>>>(xz, cw, cb, xc);
    mfma_gemm<64><<<dim3(256, 1), 256, 0, stream>>>(xc, Wx, xdbl, 40, 40, 256,
                                                    1048576, 16384, 256, 1, 1);
    dt_expand_kernel<<<512, 256, 0, stream>>>(xdbl, Wdt, bdt, dt);
    scan_kernel<<<2048, 256, 0, stream>>>(dt, xc, xz, xdbl, Alog, Dv, dt);
    mfma_gemm<128><<<dim3(256, 1), 256, 0, stream>>>(dt, Wout, outp, 128, 128, 256,
                                                     1048576, 16384, 256, 1, 1);
  };

  // row phase: A[n,k] = x[b,k,h,w], n=(b,h,w)
  run_mamba(x, 524288, 64, 1, 4096, 0,
            rWin, rcw, rcb, rWx, rWdt, rbdt, rAlog, rD, rWout, st1);
  // col phase: A[n,k] = st1[b,h,w,k], n=(b,w,h)
  run_mamba(st1, 524288, 128, 8192, 1, 1,
            cWin, ccw, ccb, cWx, cWdt, cbdt, cAlog, cD, cWout, st2);

  gn_partial_kernel<<<2048, 256, 0, stream>>>(st2, partials);
  gn_final_kernel<<<32, 64, 0, stream>>>(partials, stats);
  gn_apply_kernel<<<512, 256, 0, stream>>>(st2, stats, gamma, beta, out);
}

// Round 7
// 464.561 us; speedup vs baseline: 1.2048x; 1.0494x over previous
//
#include <hip/hip_runtime.h>
#include <math.h>

// SpaMamba: row-mamba (scan along W) -> col-mamba (scan along H) -> GroupNorm+SiLU
// B=8, C=128, H=64, W=64, D_INNER=256, D_STATE=16, D_CONV=4, DT_RANK=8, GROUPS=4
//
// GEMMs run on the matrix pipe via split-bf16 (hi+lo) x3 MFMA.
// Scan: 4-way state-split; chunked LDS staging of xc/z (coalesced) with
// register prefetch; dt computed in-kernel (dt_expand fused away); step loop
// is LDS+VALU only.

#define SILU(x) ((x) / (1.f + expf(-(x))))

typedef __attribute__((ext_vector_type(8))) short short8v;
typedef __attribute__((ext_vector_type(16))) float floatx16;

__device__ inline unsigned f32bits(float x) { return __builtin_bit_cast(unsigned, x); }
__device__ inline float bits32f(unsigned x) { return __builtin_bit_cast(float, x); }

// ---------------- MFMA split-bf16 GEMM:  C[n][j] = sum_k A[n,k] * W[j*K+k] ----------
template <int NT>
__global__ __launch_bounds__(256) void mfma_gemm(
    const float* __restrict__ A, const float* __restrict__ Wm, float* __restrict__ Cc,
    int NO, int NJ, int K, int SB, int S1, int S0, int SK, int KCONTIG) {
  __shared__ __align__(16) short Ah[128][40];
  __shared__ __align__(16) short Al[128][40];
  __shared__ __align__(16) short Wh[NT][40];
  __shared__ __align__(16) short Wl[NT][40];

  const int tid = threadIdx.x;
  const int lane = tid & 63, wave = tid >> 6;
  const int n0 = blockIdx.x * 128;
  const int j0 = blockIdx.y * NT;
  constexpr int NTW = NT / 2;
  constexpr int NSUB = NTW / 32;
  const int m_wave = (wave & 1) * 64;
  const int n_wave = (wave >> 1) * NTW;

  floatx16 acc[2][NSUB];
#pragma unroll
  for (int mt = 0; mt < 2; mt++)
#pragma unroll
    for (int nt = 0; nt < NSUB; nt++)
#pragma unroll
      for (int r = 0; r < 16; r++) acc[mt][nt][r] = 0.f;

  int mA, ksA;
  if (KCONTIG) { mA = tid >> 1; ksA = (tid & 1) * 16; }
  else         { mA = tid & 127; ksA = (tid >> 7) * 16; }
  const int nA = n0 + mA;
  const int bA = nA >> 12, m1A = (nA >> 6) & 63, m0A = nA & 63;
  const float* aRow = A + (size_t)bA * SB + (size_t)m1A * S1 + (size_t)m0A * S0;
  const int jW = tid >> 1, ksW = (tid & 1) * 16;

  const int half = lane >> 5;
  const int lrow = lane & 31;

  for (int kc = 0; kc < K; kc += 32) {
    float v[16];
    if (KCONTIG) {
      const float4* p4 = (const float4*)(aRow + kc + ksA);
#pragma unroll
      for (int q = 0; q < 4; q++) {
        float4 t = p4[q];
        v[q * 4 + 0] = t.x; v[q * 4 + 1] = t.y; v[q * 4 + 2] = t.z; v[q * 4 + 3] = t.w;
      }
    } else {
      const float* p = aRow + (size_t)(kc + ksA) * SK;
#pragma unroll
      for (int i = 0; i < 16; i++) v[i] = p[(size_t)i * SK];
    }
    unsigned uh[8], ul[8];
#pragma unroll
    for (int i = 0; i < 8; i++) {
      unsigned a0 = f32bits(v[2 * i]), a1 = f32bits(v[2 * i + 1]);
      uh[i] = __builtin_amdgcn_perm(a1, a0, 0x07060302);
      float l0 = v[2 * i] - bits32f(a0 & 0xFFFF0000u);
      float l1 = v[2 * i + 1] - bits32f(a1 & 0xFFFF0000u);
      ul[i] = __builtin_amdgcn_perm(f32bits(l1), f32bits(l0), 0x07060302);
    }
    {
      char* dh = (char*)Ah + (size_t)mA * 80 + ksA * 2;
      char* dl = (char*)Al + (size_t)mA * 80 + ksA * 2;
      ((uint4*)dh)[0] = make_uint4(uh[0], uh[1], uh[2], uh[3]);
      ((uint4*)dh)[1] = make_uint4(uh[4], uh[5], uh[6], uh[7]);
      ((uint4*)dl)[0] = make_uint4(ul[0], ul[1], ul[2], ul[3]);
      ((uint4*)dl)[1] = make_uint4(ul[4], ul[5], ul[6], ul[7]);
    }
    if (jW < NT) {
      float wv[16];
      if (j0 + jW < NJ) {
        const float4* p4 = (const float4*)(Wm + (size_t)(j0 + jW) * K + kc + ksW);
#pragma unroll
        for (int q = 0; q < 4; q++) {
          float4 t = p4[q];
          wv[q * 4 + 0] = t.x; wv[q * 4 + 1] = t.y; wv[q * 4 + 2] = t.z; wv[q * 4 + 3] = t.w;
        }
      } else {
#pragma unroll
        for (int i = 0; i < 16; i++) wv[i] = 0.f;
      }
      unsigned wh[8], wl[8];
#pragma unroll
      for (int i = 0; i < 8; i++) {
        unsigned a0 = f32bits(wv[2 * i]), a1 = f32bits(wv[2 * i + 1]);
        wh[i] = __builtin_amdgcn_perm(a1, a0, 0x07060302);
        float l0 = wv[2 * i] - bits32f(a0 & 0xFFFF0000u);
        float l1 = wv[2 * i + 1] - bits32f(a1 & 0xFFFF0000u);
        wl[i] = __builtin_amdgcn_perm(f32bits(l1), f32bits(l0), 0x07060302);
      }
      char* dh = (char*)Wh + (size_t)jW * 80 + ksW * 2;
      char* dl = (char*)Wl + (size_t)jW * 80 + ksW * 2;
      ((uint4*)dh)[0] = make_uint4(wh[0], wh[1], wh[2], wh[3]);
      ((uint4*)dh)[1] = make_uint4(wh[4], wh[5], wh[6], wh[7]);
      ((uint4*)dl)[0] = make_uint4(wl[0], wl[1], wl[2], wl[3]);
      ((uint4*)dl)[1] = make_uint4(wl[4], wl[5], wl[6], wl[7]);
    }
    __syncthreads();

#pragma unroll
    for (int s = 0; s < 2; s++) {
      const int koff = s * 32 + half * 16;
      short8v afh[2], afl[2], wfh[NSUB], wfl[NSUB];
#pragma unroll
      for (int mt = 0; mt < 2; mt++) {
        int mr = m_wave + mt * 32 + lrow;
        afh[mt] = *(const short8v*)((const char*)Ah + (size_t)mr * 80 + koff);
        afl[mt] = *(const short8v*)((const char*)Al + (size_t)mr * 80 + koff);
      }
#pragma unroll
      for (int nt = 0; nt < NSUB; nt++) {
        int nr = n_wave + nt * 32 + lrow;
        wfh[nt] = *(const short8v*)((const char*)Wh + (size_t)nr * 80 + koff);
        wfl[nt] = *(const short8v*)((const char*)Wl + (size_t)nr * 80 + koff);
      }
#pragma unroll
      for (int mt = 0; mt < 2; mt++)
#pragma unroll
        for (int nt = 0; nt < NSUB; nt++) {
          acc[mt][nt] = __builtin_amdgcn_mfma_f32_32x32x16_bf16(afh[mt], wfh[nt], acc[mt][nt], 0, 0, 0);
          acc[mt][nt] = __builtin_amdgcn_mfma_f32_32x32x16_bf16(afh[mt], wfl[nt], acc[mt][nt], 0, 0, 0);
          acc[mt][nt] = __builtin_amdgcn_mfma_f32_32x32x16_bf16(afl[mt], wfh[nt], acc[mt][nt], 0, 0, 0);
        }
    }
    __syncthreads();
  }

#pragma unroll
  for (int mt = 0; mt < 2; mt++)
#pragma unroll
    for (int nt = 0; nt < NSUB; nt++) {
      int col = j0 + n_wave + nt * 32 + lrow;
      if (col < NJ) {
#pragma unroll
        for (int r = 0; r < 16; r++) {
          int row = n0 + m_wave + mt * 32 + (r & 3) + 8 * (r >> 2) + 4 * half;
          Cc[(size_t)row * NO + col] = acc[mt][nt][r];
        }
      }
    }
}

// ---------------- causal depthwise conv (k=4) + bias + silu -----------------
__global__ __launch_bounds__(256) void conv_silu_kernel(
    const float* __restrict__ xz, const float* __restrict__ cw,
    const float* __restrict__ cb, float* __restrict__ xc) {
  int n = blockIdx.x;
  int d = threadIdx.x;
  int w = n & 63;
  float acc = cb[d];
  const float* cwd = cw + d * 4;
#pragma unroll
  for (int k = 0; k < 4; k++) {
    int ws = w - 3 + k;
    if (ws >= 0) acc = fmaf(xz[(n - 3 + k) * 512 + d], cwd[k], acc);
  }
  xc[n * 256 + d] = SILU(acc);
}

// ---------------- SSM scan: 4-way state split, chunked LDS staging, fused dt --------
// block = (seq, 64-ch slice); thread = (dl, sq) for the step loop.
// Per chunk of 16 steps: stage xc/z (coalesced float4, register-prefetched) and
// compute dt = softplus(xdbl[:, :8] @ Wdt.T + bdt) cooperatively into LDS.
// Step loop reads only LDS (broadcast-friendly patterns, no bank conflicts).
__global__ __launch_bounds__(256) void scan_kernel(
    const float* __restrict__ xcb, const float* __restrict__ xzb,
    const float* __restrict__ xdbl, const float* __restrict__ Wdt,
    const float* __restrict__ bdt, const float* __restrict__ Alog,
    const float* __restrict__ Dv, float* __restrict__ yb) {
  __shared__ float lbc[64 * 32];   // B|C per step (whole seq)
  __shared__ float lxd[64][8];     // xdbl rank slice (whole seq)
  __shared__ float xcS[16][64];    // chunk staging
  __shared__ float zS[16][64];
  __shared__ float dtS[16][64];

  const int seq = blockIdx.x >> 2;
  const int dblk = (blockIdx.x & 3) * 64;
  const int t = threadIdx.x;
  const int base = seq * 64;

  // whole-seq staging
#pragma unroll
  for (int i = 0; i < 8; i++) {
    int idx = t + i * 256;
    int w = idx >> 5, s = idx & 31;
    lbc[idx] = xdbl[(base + w) * 40 + 8 + s];
  }
#pragma unroll
  for (int i = 0; i < 2; i++) {
    int idx = t + i * 256;          // 0..511
    int w = idx >> 3, r = idx & 7;
    lxd[w][r] = xdbl[(base + w) * 40 + r];
  }

  // step-loop constants
  const int dl = t >> 2;            // 0..63
  const int sq = t & 3;             // state quarter
  const int d = dblk + dl;
  float As[4];
#pragma unroll
  for (int j = 0; j < 4; j++) As[j] = -expf(Alog[d * 16 + sq * 4 + j]);
  const float Dd = Dv[d];

  // dt-compute constants: this thread owns channel chd for 4 w-rows per chunk
  const int chd = t & 63;
  const int wq = t >> 6;            // wave id 0..3
  float wdt[8];
#pragma unroll
  for (int r = 0; r < 8; r++) wdt[r] = Wdt[(dblk + chd) * 8 + r];
  const float bdtc = bdt[dblk + chd];

  // staging map: thread -> (row sw in chunk, quad qq)
  const int sw = t >> 4, qq = t & 15;
  const float* xcp = xcb + (size_t)base * 256 + dblk + qq * 4;
  const float* zp  = xzb + (size_t)base * 512 + 256 + dblk + qq * 4;
  float4 xcR = *(const float4*)(xcp + (size_t)sw * 256);
  float4 zR  = *(const float4*)(zp  + (size_t)sw * 512);

  float h0 = 0.f, h1 = 0.f, h2 = 0.f, h3 = 0.f;
  __syncthreads();

  for (int c = 0; c < 4; c++) {
    // fill chunk LDS
    *(float4*)&xcS[sw][qq * 4] = xcR;
    *(float4*)&zS[sw][qq * 4]  = zR;
#pragma unroll
    for (int i = 0; i < 4; i++) {
      int w = wq * 4 + i;
      float4 x0 = *(const float4*)&lxd[c * 16 + w][0];
      float4 x1 = *(const float4*)&lxd[c * 16 + w][4];
      float a = bdtc;
      a = fmaf(x0.x, wdt[0], a); a = fmaf(x0.y, wdt[1], a);
      a = fmaf(x0.z, wdt[2], a); a = fmaf(x0.w, wdt[3], a);
      a = fmaf(x1.x, wdt[4], a); a = fmaf(x1.y, wdt[5], a);
      a = fmaf(x1.z, wdt[6], a); a = fmaf(x1.w, wdt[7], a);
      dtS[w][chd] = fmaxf(a, 0.f) + log1pf(expf(-fabsf(a)));
    }
    __syncthreads();
    if (c < 3) {   // register prefetch of next chunk, lands during compute
      xcR = *(const float4*)(xcp + (size_t)((c + 1) * 16 + sw) * 256);
      zR  = *(const float4*)(zp  + (size_t)((c + 1) * 16 + sw) * 512);
    }
#pragma unroll 4
    for (int wl = 0; wl < 16; wl++) {
      int w = c * 16 + wl;
      float dtv = dtS[wl][dl];
      float xcv = xcS[wl][dl];
      float zv  = zS[wl][dl];
      float dx = dtv * xcv;
      const float4 B4 = *(const float4*)(lbc + w * 32 + sq * 4);
      const float4 C4 = *(const float4*)(lbc + w * 32 + 16 + sq * 4);
      float e0 = __expf(dtv * As[0]);
      float e1 = __expf(dtv * As[1]);
      float e2 = __expf(dtv * As[2]);
      float e3 = __expf(dtv * As[3]);
      h0 = fmaf(h0, e0, dx * B4.x);
      h1 = fmaf(h1, e1, dx * B4.y);
      h2 = fmaf(h2, e2, dx * B4.z);
      h3 = fmaf(h3, e3, dx * B4.w);
      float yv = h0 * C4.x + h1 * C4.y + h2 * C4.z + h3 * C4.w;
      yv += __shfl_xor(yv, 1);
      yv += __shfl_xor(yv, 2);
      if (sq == 0) {
        float sz = zv / (1.f + __expf(-zv));
        yb[(size_t)(base + w) * 256 + d] = (yv + xcv * Dd) * sz;
      }
    }
    __syncthreads();
  }
}

// ---------------- GroupNorm stats, two-stage ----------------
__global__ __launch_bounds__(256) void gn_partial_kernel(
    const float* __restrict__ s2, double* __restrict__ partials) {
  int bg = blockIdx.x >> 6, sub = blockIdx.x & 63;
  int b = bg >> 2, g = bg & 3;
  int t = threadIdx.x;
  const float* basep = s2 + b * 524288 + g * 32 + sub * 64 * 128;
  double sum = 0.0, sumsq = 0.0;
#pragma unroll
  for (int i = 0; i < 8; i++) {
    int idx = t + i * 256;
    int c = idx & 31, sp = idx >> 5;
    float v = basep[sp * 128 + c];
    sum += v;
    sumsq += (double)v * v;
  }
  __shared__ double ls[256], lq[256];
  ls[t] = sum; lq[t] = sumsq;
  __syncthreads();
  for (int o = 128; o > 0; o >>= 1) {
    if (t < o) { ls[t] += ls[t + o]; lq[t] += lq[t + o]; }
    __syncthreads();
  }
  if (t == 0) {
    partials[blockIdx.x * 2]     = ls[0];
    partials[blockIdx.x * 2 + 1] = lq[0];
  }
}

__global__ __launch_bounds__(64) void gn_final_kernel(
    const double* __restrict__ partials, float* __restrict__ stats) {
  int bg = blockIdx.x, t = threadIdx.x;
  __shared__ double ls[64], lq[64];
  ls[t] = partials[(bg * 64 + t) * 2];
  lq[t] = partials[(bg * 64 + t) * 2 + 1];
  __syncthreads();
  for (int o = 32; o > 0; o >>= 1) {
    if (t < o) { ls[t] += ls[t + o]; lq[t] += lq[t + o]; }
    __syncthreads();
  }
  if (t == 0) {
    double mu = ls[0] / 131072.0;
    double var = lq[0] / 131072.0 - mu * mu;
    stats[bg * 2] = (float)mu;
    stats[bg * 2 + 1] = (float)(1.0 / sqrt(var + 1e-5));
  }
}

// ---------------- GN apply + silu, with LDS transpose (b,w,h,c) -> (b,c,h,w) --------
__global__ __launch_bounds__(256) void gn_apply_kernel(
    const float* __restrict__ s2, const float* __restrict__ stats,
    const float* __restrict__ gamma, const float* __restrict__ beta,
    float* __restrict__ out) {
  __shared__ float tile[64 * 129];
  int b = blockIdx.x >> 6, hh = blockIdx.x & 63;
  int t = threadIdx.x;
  const float* src = s2 + b * 524288 + hh * 128;
#pragma unroll
  for (int i = 0; i < 32; i++) {
    int idx = t + i * 256;
    int c = idx & 127, w = idx >> 7;
    tile[w * 129 + c] = src[w * 8192 + c];
  }
  __syncthreads();
  float* dst = out + b * 524288 + hh * 64;
#pragma unroll
  for (int i = 0; i < 32; i++) {
    int idx = t + i * 256;
    int w = idx & 63, c = idx >> 6;
    int g = c >> 5;
    float mu = stats[(b * 4 + g) * 2];
    float rs = stats[(b * 4 + g) * 2 + 1];
    float v = fmaf((tile[w * 129 + c] - mu) * rs, gamma[c], beta[c]);
    dst[c * 4096 + w] = SILU(v);
  }
}

extern "C" void kernel_launch(void* const* d_in, const int* in_sizes, int n_in,
                              void* d_out, int out_size, void* d_ws, size_t ws_size,
                              hipStream_t stream) {
  const float* x = (const float*)d_in[0];
  const float* rWin  = (const float*)d_in[1];
  const float* rcw   = (const float*)d_in[2];
  const float* rcb   = (const float*)d_in[3];
  const float* rWx   = (const float*)d_in[4];
  const float* rWdt  = (const float*)d_in[5];
  const float* rbdt  = (const float*)d_in[6];
  const float* rAlog = (const float*)d_in[7];
  const float* rD    = (const float*)d_in[8];
  const float* rWout = (const float*)d_in[9];
  const float* cWin  = (const float*)d_in[10];
  const float* ccw   = (const float*)d_in[11];
  const float* ccb   = (const float*)d_in[12];
  const float* cWx   = (const float*)d_in[13];
  const float* cWdt  = (const float*)d_in[14];
  const float* cbdt  = (const float*)d_in[15];
  const float* cAlog = (const float*)d_in[16];
  const float* cD    = (const float*)d_in[17];
  const float* cWout = (const float*)d_in[18];
  const float* gamma = (const float*)d_in[19];
  const float* beta  = (const float*)d_in[20];
  float* out = (float*)d_out;

  float* ws = (float*)d_ws;
  float* xz    = ws;                    // 16,777,216
  float* xc    = xz  + 16777216;        //  8,388,608
  float* yb    = xc  + 8388608;         //  8,388,608  (scan output y*silu(z))
  float* st1   = yb  + 8388608;         //  4,194,304
  float* stats = st1 + 4194304;         //  64
  double* partials = (double*)(stats + 64);
  float* xdbl  = st1;                   // overlay: st1 dead while xdbl lives
  float* st2   = xc;                    // overlay: xc dead when stage2 written

  auto run_mamba = [&](const float* A, int SB, int S1, int S0, int SK, int KCONTIG,
                       const float* Win, const float* cw, const float* cb,
                       const float* Wx, const float* Wdt, const float* bdt,
                       const float* Alog, const float* Dv, const float* Wout,
                       float* outp) {
    mfma_gemm<128><<<dim3(256, 4), 256, 0, stream>>>(A, Win, xz, 512, 512, 128,
                                                     SB, S1, S0, SK, KCONTIG);
    conv_silu_kernel<<<32768, 256, 0, stream>>>(xz, cw, cb, xc);
    mfma_gemm<64><<<dim3(256, 1), 256, 0, stream>>>(xc, Wx, xdbl, 40, 40, 256,
                                                    1048576, 16384, 256, 1, 1);
    scan_kernel<<<2048, 256, 0, stream>>>(xc, xz, xdbl, Wdt, bdt, Alog, Dv, yb);
    mfma_gemm<128><<<dim3(256, 1), 256, 0, stream>>>(yb, Wout, outp, 128, 128, 256,
                                                     1048576, 16384, 256, 1, 1);
  };

  // row phase: A[n,k] = x[b,k,h,w], n=(b,h,w)
  run_mamba(x, 524288, 64, 1, 4096, 0,
            rWin, rcw, rcb, rWx, rWdt, rbdt, rAlog, rD, rWout, st1);
  // col phase: A[n,k] = st1[b,h,w,k], n=(b,w,h)
  run_mamba(st1, 524288, 128, 8192, 1, 1,
            cWin, ccw, ccb, cWx, cWdt, cbdt, cAlog, cD, cWout, st2);

  gn_partial_kernel<<<2048, 256, 0, stream>>>(st2, partials);
  gn_final_kernel<<<32, 64, 0, stream>>>(partials, stats);
  gn_apply_kernel<<<512, 256, 0, stream>>>(st2, stats, gamma, beta, out);
}